// Round 15
// baseline (166.438 us; speedup 1.0000x reference)
//
#include <hip/hip_runtime.h>
#include <math.h>

// NoRefRetIQANet: cosine top-K retrieval via fp16 2-split MFMA.
//   score[b,n] = dot(q_b, d_n) / ||d_n||  (query norm skipped: order-invariant)
//   x = hi + lo/4096;  dot = hh + (hl + lh)/4096  (ll term ~2^-24, dropped)
// Round-15: BN=256 (one variable vs R14). Per-wave step shape IDENTICAL to
// R12/R14's proven rhythm (K-step 32, wave tile 32q x 64n, 5 DMA/wave/step,
// two-barrier loop, vmcnt(5)). A amortized over 2x more columns: staged
// bytes 722 -> 601 MB. 237 blocks = 79 n-tiles x {sem kc0, sem kc1, dst};
// 512 thr / 8 waves (2qh x 4nh); ring-2 LDS 80 KB (A 2x8 + B 2x32).
// Tail: R12 banked tail verbatim (segmented top-16 + merge-gather).
// ws: semp0[64][20000] f32, semp1, dstp, nsq0/1/d[20000], apack_sem(hi+lo),
//     apack_dst(hi+lo), cand_val[128][128], cand_idx[128][128].
// d_out: [0,64) result, [64, 64+64*18) retrieved.

typedef _Float16 half8 __attribute__((ext_vector_type(8)));
typedef float    f32x4 __attribute__((ext_vector_type(4)));

#define NDB   20000
#define NQ    64
#define KSEM  4096
#define KDST  2048
#define KC    2048
#define NSTEP (KC / 32)     // 64 steps of 32
#define BN    256
#define NTILE 79            // ceil(20000/256); last tile row-clamped
#define K2    16
#define SEG   8
#define SEGSZ (NDB / SEG)   // 2500

__device__ __forceinline__ void async_cp16(const void* g, void* l) {
    __builtin_amdgcn_global_load_lds(
        (const __attribute__((address_space(1))) void*)g,
        (__attribute__((address_space(3))) void*)l, 16, 0, 0);
}

// ---------------------------------------------------------------------------
// qsplit: fp32 queries -> fragment-ordered, bank-swizzled f16 hi/lo pack.
// Unit u (16B = half8) within a 32-k section: u = 4*row + (((row>>1)&3)^kg);
// section = 512 units: [0,256) hi, [256,512) lo.  (verified rounds 3-6,12,14)
// ---------------------------------------------------------------------------
__global__ __launch_bounds__(256) void qsplit_kernel(
    const float* __restrict__ fc, const float* __restrict__ fd,
    _Float16* __restrict__ apack_sem, _Float16* __restrict__ apack_dst)
{
    const int idx = (int)blockIdx.x * 256 + (int)threadIdx.x;
    const int NSEM8 = NQ * KSEM / 8;            // 32768
    const float* src; _Float16* dst; int row, g8, K;
    if (idx < NSEM8) { src = fc; dst = apack_sem; K = KSEM; row = idx >> 9; g8 = idx & 511; }
    else { const int j = idx - NSEM8; src = fd; dst = apack_dst; K = KDST; row = j >> 8; g8 = j & 255; }

    const float* p = src + (size_t)row * K + g8 * 8;
    const float4 v0 = ((const float4*)p)[0];
    const float4 v1 = ((const float4*)p)[1];
    const float xs[8] = {v0.x, v0.y, v0.z, v0.w, v1.x, v1.y, v1.z, v1.w};
    half8 hi, lo;
    #pragma unroll
    for (int e = 0; e < 8; ++e) {
        const _Float16 h = (_Float16)xs[e];
        hi[e] = h;
        lo[e] = (_Float16)((xs[e] - (float)h) * 4096.0f);
    }
    const int sec = g8 >> 2, kg = g8 & 3;
    const int u = (row << 2) + (((row >> 1) & 3) ^ kg);
    half8* d8 = (half8*)dst;
    d8[sec * 512 + u]       = hi;
    d8[sec * 512 + 256 + u] = lo;
}

// ---------------------------------------------------------------------------
// score: 237 blocks = 79 n-tiles x {sem kc0, sem kc1, dst}, uniform KC=2048.
// 512 thr / 8 waves, wave grid 2x4 (qh=w>>2, nh=w&3), wave tile 32q x 64n.
// ---------------------------------------------------------------------------
__global__ __launch_bounds__(512, 1) void score_kernel(
    const float* __restrict__ sdb, const float* __restrict__ ddb,
    const _Float16* __restrict__ apack_sem, const _Float16* __restrict__ apack_dst,
    float* __restrict__ semp0, float* __restrict__ semp1, float* __restrict__ dstp,
    float* __restrict__ nsq0, float* __restrict__ nsq1, float* __restrict__ nsqd)
{
    // A: [buf][hi 2048 | lo 2048] halves; 8 KB/buf
    __shared__ __align__(16) _Float16 A_lds[2][4096];
    // B: [buf][r*32 + cphys*4] floats, 256 rows; 32 KB/buf
    __shared__ __align__(16) float    B_lds[2][8192];

    const int tid  = threadIdx.x;
    const int lane = tid & 63, w = tid >> 6;          // w in [0,8)
    const int bid  = (int)blockIdx.x;
    const int mkc  = bid / NTILE;         // 0: sem kc0, 1: sem kc1, 2: dst
    const int nt   = bid % NTILE;
    const int n0   = nt * BN;

    const float* D; const _Float16* AP; float *SOUT, *NOUT; int Ks, koff;
    if (mkc == 0)      { D=sdb; AP=apack_sem; SOUT=semp0; NOUT=nsq0; Ks=KSEM; koff=0;  }
    else if (mkc == 1) { D=sdb; AP=apack_sem; SOUT=semp1; NOUT=nsq1; Ks=KSEM; koff=KC; }
    else               { D=ddb; AP=apack_dst; SOUT=dstp;  NOUT=nsqd; Ks=KDST; koff=0;  }

    // --- B staging: 32 insts/step, 4 per wave; unit u = w*256 + k2*64 + lane
    const float* gBp[4];
    #pragma unroll
    for (int k2 = 0; k2 < 4; ++k2) {
        const int u = w * 256 + k2 * 64 + lane;       // [0, 2048)
        const int r = u >> 3;                         // [0, 256)
        const int c = (u & 7) ^ (r & 7);
        const int rg = (n0 + r < NDB) ? n0 + r : NDB - 1;   // clamp tail tile
        gBp[k2] = D + (size_t)rg * Ks + koff + c * 4;
    }
    // --- A staging: 8 insts/step, 1 per wave; units w*64+lane of 512
    const uint4* gA = (const uint4*)AP + ((size_t)koff >> 5) * 512 + w * 64 + lane;

    // --- compute map ---
    const int lr = lane & 15, kg = lane >> 4;
    const int qh = w >> 2, nh = w & 3;
    const int rowA0 = qh * 32 + lr;
    const int rowA1 = rowA0 + 16;
    const int uA0 = ((rowA0 << 2) + (((rowA0 >> 1) & 3) ^ kg)) * 8;
    const int uA1 = ((rowA1 << 2) + (((rowA1 >> 1) & 3) ^ kg)) * 8;
    int oB0[4], oB1[4];
    #pragma unroll
    for (int j = 0; j < 4; ++j) {
        const int rB = nh * 64 + j * 16 + lr;
        oB0[j] = rB * 32 + (((kg * 2 + 0) ^ (rB & 7)) << 2);
        oB1[j] = rB * 32 + (((kg * 2 + 1) ^ (rB & 7)) << 2);
    }

    f32x4 acc_h[2][4], acc_x[2][4];
    const f32x4 zz = {0.f, 0.f, 0.f, 0.f};
    #pragma unroll
    for (int i = 0; i < 2; ++i)
        #pragma unroll
        for (int j = 0; j < 4; ++j) { acc_h[i][j] = zz; acc_x[i][j] = zz; }
    float sq[4] = {0.f, 0.f, 0.f, 0.f};

    auto STAGE = [&](int s, int buf) {
        async_cp16(gA + (size_t)s * 512, &A_lds[buf][w * 512]);   // hi or lo quarter
        #pragma unroll
        for (int k2 = 0; k2 < 4; ++k2)
            async_cp16(gBp[k2] + (size_t)s * 32, &B_lds[buf][w * 1024 + k2 * 256]);
    };

    auto COMPUTE = [&](int buf) {
        const float*    Bb = &B_lds[buf][0];
        const _Float16* Ab = &A_lds[buf][0];
        half8 bh[4], bl[4];
        #pragma unroll
        for (int j = 0; j < 4; ++j) {
            const f32x4 p = *(const f32x4*)(Bb + oB0[j]);
            const f32x4 q = *(const f32x4*)(Bb + oB1[j]);
            const float xs[8] = {p[0], p[1], p[2], p[3], q[0], q[1], q[2], q[3]};
            #pragma unroll
            for (int e = 0; e < 8; ++e) {
                const float x = xs[e];
                sq[j] = fmaf(x, x, sq[j]);
                const _Float16 h = (_Float16)x;
                bh[j][e] = h;
                bl[j][e] = (_Float16)((x - (float)h) * 4096.0f);
            }
        }
        const half8 ah0 = *(const half8*)(Ab + uA0);
        const half8 av0 = *(const half8*)(Ab + 2048 + uA0);
        const half8 ah1 = *(const half8*)(Ab + uA1);
        const half8 av1 = *(const half8*)(Ab + 2048 + uA1);
        #pragma unroll
        for (int j = 0; j < 4; ++j) {
            acc_h[0][j] = __builtin_amdgcn_mfma_f32_16x16x32_f16(ah0, bh[j], acc_h[0][j], 0, 0, 0);
            acc_x[0][j] = __builtin_amdgcn_mfma_f32_16x16x32_f16(ah0, bl[j], acc_x[0][j], 0, 0, 0);
            acc_x[0][j] = __builtin_amdgcn_mfma_f32_16x16x32_f16(av0, bh[j], acc_x[0][j], 0, 0, 0);
            acc_h[1][j] = __builtin_amdgcn_mfma_f32_16x16x32_f16(ah1, bh[j], acc_h[1][j], 0, 0, 0);
            acc_x[1][j] = __builtin_amdgcn_mfma_f32_16x16x32_f16(ah1, bl[j], acc_x[1][j], 0, 0, 0);
            acc_x[1][j] = __builtin_amdgcn_mfma_f32_16x16x32_f16(av1, bh[j], acc_x[1][j], 0, 0, 0);
        }
    };

    // prologue: 2 steps staged (10 DMAs/wave outstanding)
    STAGE(0, 0); STAGE(1, 1);

    for (int s = 0; s < NSTEP; ++s) {
        if (s < NSTEP - 1) { asm volatile("s_waitcnt vmcnt(5)" ::: "memory"); }
        else               { asm volatile("s_waitcnt vmcnt(0)" ::: "memory"); }
        __builtin_amdgcn_s_barrier();      // step-s data visible to all waves
        COMPUTE(s & 1);
        __builtin_amdgcn_s_barrier();      // all waves done reading buf s&1
        if (s + 2 < NSTEP) STAGE(s + 2, s & 1);
    }

    // norms (exact f32 sum-sq of raw B): sq[j] covers col nh*64+j*16+lr over
    // this lane's kg quarter; reduce over kg (xor 16,32); qh==0 waves write.
    #pragma unroll
    for (int j = 0; j < 4; ++j) {
        sq[j] += __shfl_xor(sq[j], 16);
        sq[j] += __shfl_xor(sq[j], 32);
    }
    if (qh == 0 && lane < 16) {
        #pragma unroll
        for (int j = 0; j < 4; ++j) {
            const int nn = n0 + nh * 64 + j * 16 + lane;
            if (nn < NDB) NOUT[nn] = sq[j];
        }
    }

    // C/D map: col=lane&15, row=(lane>>4)*4+reg (m89-verified)
    #pragma unroll
    for (int i = 0; i < 2; ++i)
        #pragma unroll
        for (int j = 0; j < 4; ++j) {
            const int n = n0 + nh * 64 + j * 16 + lr;
            if (n < NDB) {
                #pragma unroll
                for (int rr = 0; rr < 4; ++rr) {
                    const int q = qh * 32 + i * 16 + kg * 4 + rr;
                    SOUT[(size_t)q * NDB + n] = acc_h[i][j][rr] + acc_x[i][j][rr] * (1.0f / 4096.0f);
                }
            }
        }
}

// ---------------------------------------------------------------------------
// topk_seg: EXACT top-16 per (m,b,segment). 1024 blocks. (R12 verbatim)
// Comparator: value desc, index asc (matches lax.top_k).
// ---------------------------------------------------------------------------
__global__ __launch_bounds__(256) void topk_seg_kernel(
    const float* __restrict__ semp0, const float* __restrict__ semp1,
    const float* __restrict__ dstp,
    const float* __restrict__ nsq0, const float* __restrict__ nsq1,
    const float* __restrict__ nsqd,
    float* __restrict__ cand_val, int* __restrict__ cand_idx)
{
    __shared__ float sv[256][K2];
    __shared__ int   si[256][K2];

    const int tid = threadIdx.x;
    const int mb  = (int)blockIdx.x >> 3;      // m*64 + b
    const int seg = (int)blockIdx.x & 7;
    const int b = mb & 63;
    const int m = mb >> 6;

    float v[K2]; int ix[K2];
    #pragma unroll
    for (int k = 0; k < K2; ++k) { v[k] = -INFINITY; ix[k] = 0x7fffffff; }

    const size_t roff = (size_t)b * NDB;
    const int iend = (seg + 1) * SEGSZ;
    for (int i = seg * SEGSZ + tid; i < iend; i += 256) {
        float sval;
        if (m == 0) {
            sval = (semp0[roff + i] + semp1[roff + i]) * (1.0f / sqrtf(nsq0[i] + nsq1[i]));
        } else {
            sval = dstp[roff + i] * (1.0f / sqrtf(nsqd[i]));
        }
        if (sval > v[0]) {
            bool bt[K2];
            bt[0] = true;
            #pragma unroll
            for (int j = 1; j < K2; ++j) bt[j] = sval > v[j];
            #pragma unroll
            for (int j = 0; j < K2 - 1; ++j) {
                v[j]  = bt[j+1] ? v[j+1]  : (bt[j] ? sval : v[j]);
                ix[j] = bt[j+1] ? ix[j+1] : (bt[j] ? i    : ix[j]);
            }
            v[K2-1]  = bt[K2-1] ? sval : v[K2-1];
            ix[K2-1] = bt[K2-1] ? i    : ix[K2-1];
        }
    }

    #pragma unroll
    for (int k = 0; k < K2; ++k) { sv[tid][k] = v[k]; si[tid][k] = ix[k]; }
    __syncthreads();

    for (int s2 = 128; s2 >= 1; s2 >>= 1) {
        if (tid < s2) {
            float rv[K2]; int ri[K2];
            int pa = K2 - 1, pb = K2 - 1;
            #pragma unroll
            for (int k = K2 - 1; k >= 0; --k) {
                const float va = sv[tid][pa];      const int ia = si[tid][pa];
                const float vb = sv[tid + s2][pb]; const int ib = si[tid + s2][pb];
                const bool takeA = (va > vb) || (va == vb && ia < ib);
                rv[k] = takeA ? va : vb;
                ri[k] = takeA ? ia : ib;
                if (takeA) --pa; else --pb;
            }
            #pragma unroll
            for (int k = 0; k < K2; ++k) { sv[tid][k] = rv[k]; si[tid][k] = ri[k]; }
        }
        __syncthreads();
    }

    if (tid < K2) {
        cand_val[(size_t)mb * 128 + seg * K2 + tid] = sv[0][K2 - 1 - tid];
        cand_idx[(size_t)mb * 128 + seg * K2 + tid] = si[0][K2 - 1 - tid];
    }
}

// ---------------------------------------------------------------------------
// merge: rank the 128 segment candidates per (m,b); rank<9 gathers metrics
// straight into retrieved[b][2*rank+m]. (R12 verbatim)
// ---------------------------------------------------------------------------
__global__ __launch_bounds__(128) void merge_kernel(
    const float* __restrict__ cand_val, const int* __restrict__ cand_idx,
    const float* __restrict__ metrics, float* __restrict__ out_ret)
{
    __shared__ float v[128];
    __shared__ int   id[128];
    const int tid = threadIdx.x;
    const int mb  = (int)blockIdx.x;
    const int b = mb & 63;
    const int m = mb >> 6;
    v[tid]  = cand_val[(size_t)mb * 128 + tid];
    id[tid] = cand_idx[(size_t)mb * 128 + tid];
    __syncthreads();
    const float mv = v[tid];
    const int   mi = id[tid];
    int rank = 0;
    for (int j = 0; j < 128; ++j)
        rank += (v[j] > mv) || (v[j] == mv && id[j] < mi);
    if (rank < 9) out_ret[(size_t)b * 18 + 2 * rank + m] = metrics[mi];
}

// result[b] = mean(retrieved[b][0..17])
__global__ void finalize_kernel(float* __restrict__ d_out)
{
    const int b = threadIdx.x;
    const float* r = d_out + 64 + (size_t)b * 18;
    float s = 0.f;
    #pragma unroll
    for (int j = 0; j < 18; ++j) s += r[j];
    d_out[b] = s * (1.0f / 18.0f);
}

extern "C" void kernel_launch(void* const* d_in, const int* in_sizes, int n_in,
                              void* d_out, int out_size, void* d_ws, size_t ws_size,
                              hipStream_t stream)
{
    const float* fc  = (const float*)d_in[0];   // [64][4096]
    const float* fd  = (const float*)d_in[1];   // [64][2048]
    const float* sdb = (const float*)d_in[2];   // [20000][4096]
    const float* ddb = (const float*)d_in[3];   // [20000][2048]
    const float* met = (const float*)d_in[4];   // [20000]

    float* semp0 = (float*)d_ws;
    float* semp1 = semp0 + (size_t)NQ * NDB;
    float* dstp  = semp1 + (size_t)NQ * NDB;
    float* nsq0  = dstp  + (size_t)NQ * NDB;
    float* nsq1  = nsq0 + NDB;
    float* nsqd  = nsq1 + NDB;
    _Float16* apack_sem = (_Float16*)(nsqd + NDB);           // hi+lo: 1 MB
    _Float16* apack_dst = apack_sem + (size_t)NQ * KSEM * 2; // hi+lo: 0.5 MB
    float* cand_val = (float*)(apack_dst + (size_t)NQ * KDST * 2);  // 128*128
    int*   cand_idx = (int*)(cand_val + 128 * 128);                 // 128*128

    float* out = (float*)d_out;

    qsplit_kernel<<<dim3(192), dim3(256), 0, stream>>>(fc, fd, apack_sem, apack_dst);
    score_kernel<<<dim3(3 * NTILE), dim3(512), 0, stream>>>(
        sdb, ddb, apack_sem, apack_dst, semp0, semp1, dstp, nsq0, nsq1, nsqd);
    topk_seg_kernel<<<dim3(128 * SEG), dim3(256), 0, stream>>>(
        semp0, semp1, dstp, nsq0, nsq1, nsqd, cand_val, cand_idx);
    merge_kernel<<<dim3(128), dim3(128), 0, stream>>>(cand_val, cand_idx, met, out + 64);
    finalize_kernel<<<dim3(1), dim3(64), 0, stream>>>(out);
}